// Round 1
// baseline (51257.025 us; speedup 1.0000x reference)
//
#include <hip/hip_runtime.h>
#include <hip/hip_cooperative_groups.h>
#include <math.h>

namespace cg = cooperative_groups;

// GRU layer: B=64, T=512, I=512, H=1024, fp32.
// PERSISTENT cooperative kernel: one launch, grid.sync() per timestep.
// h-history stored in d_out itself: out[b][t][:] == h_t; step t reads t-1.
// Each block owns JB=4 hidden indices j (all 3 gates, all 64 batch rows).
// Grid = H/JB = 256 blocks (one per CU), 256 threads.
// K-loop over 1536 (512 x-part via W_i_*, 1024 h-part via W_h_*) in CK=128
// chunks, register double-buffered into LDS (T14 async-STAGE split):
// chunk c+1's global loads are issued right after chunk c's barrier and
// consumed one chunk later, so no vmcnt(0)-at-barrier drain.

#define BB 64
#define TT 512
#define II 512
#define HH 1024
#define JB 4
#define CK 128
#define PAD 132   // 132*4B = 528B row stride: 16B-aligned, 8-per-bank balanced

__device__ __forceinline__ void fma4(float4& a, const float4 xv, const float4 w) {
    a.x += xv.x * w.x;
    a.y += xv.y * w.y;
    a.z += xv.z * w.z;
    a.w += xv.w * w.w;
}

__device__ __forceinline__ void accum_chunk(
    const float* __restrict__ xsrow,
    const float* __restrict__ wr, const float* __restrict__ wz,
    const float* __restrict__ wn,
    float4& aR, float4& aZ, float4& aN)
{
#pragma unroll
    for (int k4 = 0; k4 < CK / 4; ++k4) {
        float4 xv = *(const float4*)(xsrow + k4 * 4);
        fma4(aR, xv, *(const float4*)(wr + k4 * 4));
        fma4(aZ, xv, *(const float4*)(wz + k4 * 4));
        fma4(aN, xv, *(const float4*)(wn + k4 * 4));
    }
}

// Issue the 8 coalesced float4 loads of one 64x128 tile into registers.
__device__ __forceinline__ void issue_chunk(
    float4 (&st)[8], const float* __restrict__ base, size_t rowstride,
    int koff, int tid)
{
#pragma unroll
    for (int i = 0; i < 8; ++i) {
        int f   = tid + 256 * i;
        int row = f >> 5;           // 32 float4 per row
        int c4  = f & 31;
        st[i] = *(const float4*)(base + (size_t)row * rowstride + koff + c4 * 4);
    }
}

__global__ __launch_bounds__(256, 1) void gru_persistent(
    const float* __restrict__ x,
    const float* __restrict__ Wir, const float* __restrict__ Whr,
    const float* __restrict__ Wiz, const float* __restrict__ Whz,
    const float* __restrict__ Win, const float* __restrict__ Whn,
    const float* __restrict__ bir, const float* __restrict__ bhr,
    const float* __restrict__ biz, const float* __restrict__ bhz,
    const float* __restrict__ bin_, const float* __restrict__ bhn,
    float* __restrict__ out)
{
    __shared__ float xs[2][BB][PAD];   // double-buffered 64x128 tile
    cg::grid_group grid = cg::this_grid();

    const int tid = threadIdx.x;
    const int b   = tid & 63;
    const int jg  = tid >> 6;                      // 0..3, wave-uniform
    const int j   = __builtin_amdgcn_readfirstlane((int)blockIdx.x * JB + jg);

    // hoist bias LOADS (add order in epilogue kept identical to baseline)
    const float bir_j = bir[j], bhr_j = bhr[j];
    const float biz_j = biz[j], bhz_j = bhz[j];
    const float bin_j = bin_[j], bhn_j = bhn[j];

    float4 st[8];
    // prefetch x chunk 0 of t = 0
    issue_chunk(st, x, (size_t)TT * II, 0, tid);

    for (int t = 0; t < TT; ++t) {
        float4 aR  = {0.f, 0.f, 0.f, 0.f};
        float4 aZ  = {0.f, 0.f, 0.f, 0.f};
        float4 aXN = {0.f, 0.f, 0.f, 0.f};
        float4 aHN = {0.f, 0.f, 0.f, 0.f};

        const float* xbase = x   + (size_t)t * II;
        const float* hbase = out + (size_t)(t - 1) * HH;   // valid for t>0
        const int nch = (t > 0) ? 12 : 4;   // 4 x-chunks + 8 h-chunks

        for (int c = 0; c < nch; ++c) {
            const int bufi = c & 1;
            // write previously-loaded registers to LDS
#pragma unroll
            for (int i = 0; i < 8; ++i) {
                const int f = tid + 256 * i;
                *(float4*)&xs[bufi][f >> 5][(f & 31) * 4] = st[i];
            }
            __syncthreads();
            // issue next chunk's loads; latency hides under accum below
            if (c + 1 < nch) {
                if (c + 1 < 4)
                    issue_chunk(st, xbase, (size_t)TT * II, (c + 1) * CK, tid);
                else
                    issue_chunk(st, hbase, (size_t)TT * HH, (c + 1 - 4) * CK, tid);
            }
            if (c < 4) {
                accum_chunk(&xs[bufi][b][0],
                            Wir + (size_t)j * II + c * CK,
                            Wiz + (size_t)j * II + c * CK,
                            Win + (size_t)j * II + c * CK,
                            aR, aZ, aXN);
            } else {
                const int kc = c - 4;
                accum_chunk(&xs[bufi][b][0],
                            Whr + (size_t)j * HH + kc * CK,
                            Whz + (size_t)j * HH + kc * CK,
                            Whn + (size_t)j * HH + kc * CK,
                            aR, aZ, aHN);
            }
            // no trailing barrier: double buffer + next iter's barrier
            // guarantee no wave writes a buffer another wave still reads
        }

        // ---------- epilogue: gates + state update (same order as baseline) ----------
        float rpre = (aR.x + aR.y + aR.z + aR.w) + bir_j + bhr_j;
        float zpre = (aZ.x + aZ.y + aZ.z + aZ.w) + biz_j + bhz_j;
        float hn   = (aHN.x + aHN.y + aHN.z + aHN.w) + bhn_j;
        float xn   = (aXN.x + aXN.y + aXN.z + aXN.w) + bin_j;

        float r = 1.f / (1.f + __expf(-rpre));
        float z = 1.f / (1.f + __expf(-zpre));
        float n = tanhf(xn + r * hn);

        float hprev = (t > 0) ? out[(size_t)b * (TT * HH) + (size_t)(t - 1) * HH + j] : 0.f;
        out[(size_t)b * (TT * HH) + (size_t)t * HH + j] = (1.f - z) * n + z * hprev;

        // prefetch next step's first x chunk BEFORE the grid barrier so the
        // loads fly during sync
        if (t + 1 < TT)
            issue_chunk(st, xbase + II, (size_t)TT * II, 0, tid);

        grid.sync();   // h_t visible to all blocks (device-scope fence incl.)
    }
}

extern "C" void kernel_launch(void* const* d_in, const int* in_sizes, int n_in,
                              void* d_out, int out_size, void* d_ws, size_t ws_size,
                              hipStream_t stream) {
    (void)in_sizes; (void)n_in; (void)d_ws; (void)ws_size; (void)out_size;

    const float* x    = (const float*)d_in[0];
    const float* Wir  = (const float*)d_in[1];
    const float* bir  = (const float*)d_in[2];
    const float* Whr  = (const float*)d_in[3];
    const float* bhr  = (const float*)d_in[4];
    const float* Wiz  = (const float*)d_in[5];
    const float* biz  = (const float*)d_in[6];
    const float* Whz  = (const float*)d_in[7];
    const float* bhz  = (const float*)d_in[8];
    const float* Win  = (const float*)d_in[9];
    const float* bin_ = (const float*)d_in[10];
    const float* Whn  = (const float*)d_in[11];
    const float* bhn  = (const float*)d_in[12];
    float* out = (float*)d_out;

    void* args[] = { &x, &Wir, &Whr, &Wiz, &Whz, &Win, &Whn,
                     &bir, &bhr, &biz, &bhz, &bin_, &bhn, &out };

    hipLaunchCooperativeKernel((const void*)gru_persistent,
                               dim3(HH / JB), dim3(256), args, 0, stream);
}

// Round 2
// 29302.917 us; speedup vs baseline: 1.7492x; 1.7492x over previous
//
#include <hip/hip_runtime.h>
#include <math.h>

// GRU layer: B=64, T=512, I=512, H=1024, fp32.
// One launch per timestep (grid.sync proved catastrophic: full L2
// writeback/invalidate per sync, 17.9MB HBM writes/step — rocprof r1).
//
// Structure per step:
//   grid = 256 blocks (1/CU), 512 threads = 8 waves -> 2 waves/SIMD.
//   Each block owns JB=4 hidden j; wave sel=tid>>6: jloc=sel&3, kh=sel>>2.
//   Split-K: kh=0 -> x k[0,256)+h k[0,512); kh=1 -> x k[256,512)+h k[512,1024).
//   x-part staged in LDS (2 phases, both K-halves staged together).
//   h-part: ZERO barriers — h kept in transposed packed layout
//   htpack[parity][k/4][b][4] (d_ws, 512KB double buffer) so lane b reads
//   coalesced float4 directly from L2; compiler pipelines freely.
//   Epilogue: kh=1 partials -> LDS -> kh=0 combines, gates, writes
//   out[b][t][j] and htpack[t&1].

#define BB 64
#define TT 512
#define II 512
#define HH 1024
#define JB 4
#define KHX 256    // per-half K in x-part
#define KHH 512    // per-half K in h-part
#define PAD 132    // 528B row stride: 16B-aligned, balanced banks

__device__ __forceinline__ void fma4(float4& a, const float4 xv, const float4 w) {
    a.x += xv.x * w.x;
    a.y += xv.y * w.y;
    a.z += xv.z * w.z;
    a.w += xv.w * w.w;
}

__global__ __launch_bounds__(512, 2) void gru_step(
    const float* __restrict__ x,
    const float* __restrict__ Wir, const float* __restrict__ Whr,
    const float* __restrict__ Wiz, const float* __restrict__ Whz,
    const float* __restrict__ Win, const float* __restrict__ Whn,
    const float* __restrict__ bir, const float* __restrict__ bhr,
    const float* __restrict__ biz, const float* __restrict__ bhz,
    const float* __restrict__ bin_, const float* __restrict__ bhn,
    float* __restrict__ out, float* __restrict__ htpack, int t)
{
    __shared__ float xs[2][BB][PAD];   // [kh][row][128 floats]
    const int tid  = threadIdx.x;
    const int b    = tid & 63;
    const int sel  = tid >> 6;          // 0..7 (wave id)
    const int jloc = sel & 3;
    const int kh   = sel >> 2;          // K-half selector
    const int j    = __builtin_amdgcn_readfirstlane((int)blockIdx.x * JB + jloc);

    const float bir_j = bir[j], bhr_j = bhr[j];
    const float biz_j = biz[j], bhz_j = bhz[j];
    const float bin_j = bin_[j], bhn_j = bhn[j];

    float4 aR  = {0.f, 0.f, 0.f, 0.f};
    float4 aZ  = {0.f, 0.f, 0.f, 0.f};
    float4 aXN = {0.f, 0.f, 0.f, 0.f};
    float4 aHN = {0.f, 0.f, 0.f, 0.f};

    // ---------------- x part: 2 phases, both K-halves per phase ----------
    const float* xbase = x + (size_t)t * II;
    for (int p = 0; p < 2; ++p) {
        // stage 128 virtual rows (2 chunks x 64 rows x 128 floats = 64KB)
#pragma unroll
        for (int i = 0; i < 8; ++i) {
            int f    = tid + 512 * i;
            int vrow = f >> 5;            // 0..127
            int c4   = f & 31;
            int row  = vrow & 63;
            int half = vrow >> 6;         // which K-half this chunk feeds
            int koff = half * KHX + p * 128;
            *(float4*)&xs[half][row][c4 * 4] =
                *(const float4*)(xbase + (size_t)row * (TT * II) + koff + c4 * 4);
        }
        __syncthreads();
        {
            const float* xsrow = &xs[kh][b][0];
            const int kw = kh * KHX + p * 128;   // weight K offset
            const float* wr = Wir + (size_t)j * II + kw;
            const float* wz = Wiz + (size_t)j * II + kw;
            const float* wn = Win + (size_t)j * II + kw;
#pragma unroll
            for (int k4 = 0; k4 < 32; ++k4) {
                float4 xv = *(const float4*)(xsrow + k4 * 4);
                fma4(aR,  xv, *(const float4*)(wr + k4 * 4));
                fma4(aZ,  xv, *(const float4*)(wz + k4 * 4));
                fma4(aXN, xv, *(const float4*)(wn + k4 * 4));
            }
        }
        __syncthreads();
    }

    // ---------------- h part: barrier-free, coalesced from htpack --------
    if (t > 0) {
        const float* hp = htpack + (size_t)((t - 1) & 1) * (HH * BB);
        const int kbase = kh * KHH;                   // element offset in K
        const float* hrow = hp + (size_t)(kbase >> 2) * (BB * 4) + b * 4;
        const float* wr = Whr + (size_t)j * HH + kbase;
        const float* wz = Whz + (size_t)j * HH + kbase;
        const float* wn = Whn + (size_t)j * HH + kbase;
#pragma unroll 4
        for (int k4 = 0; k4 < KHH / 4; ++k4) {
            float4 hv = *(const float4*)(hrow + (size_t)k4 * (BB * 4));
            fma4(aR,  hv, *(const float4*)(wr + k4 * 4));
            fma4(aZ,  hv, *(const float4*)(wz + k4 * 4));
            fma4(aHN, hv, *(const float4*)(wn + k4 * 4));
        }
    }

    // ---------------- split-K reduction + epilogue -----------------------
    __syncthreads();                       // everyone done reading xs
    float* red = &xs[0][0][0];             // reuse LDS: [4j][64b][4] floats
    if (kh == 1) {
        float* r4 = red + ((jloc * 64 + b) * 4);
        r4[0] = aR.x + aR.y + aR.z + aR.w;
        r4[1] = aZ.x + aZ.y + aZ.z + aZ.w;
        r4[2] = aXN.x + aXN.y + aXN.z + aXN.w;
        r4[3] = aHN.x + aHN.y + aHN.z + aHN.w;
    }
    __syncthreads();
    if (kh == 0) {
        const float* r4 = red + ((jloc * 64 + b) * 4);
        float rpre = (aR.x + aR.y + aR.z + aR.w) + r4[0] + bir_j + bhr_j;
        float zpre = (aZ.x + aZ.y + aZ.z + aZ.w) + r4[1] + biz_j + bhz_j;
        float xn   = (aXN.x + aXN.y + aXN.z + aXN.w) + r4[2] + bin_j;
        float hn   = (aHN.x + aHN.y + aHN.z + aHN.w) + r4[3] + bhn_j;

        float r = 1.f / (1.f + __expf(-rpre));
        float z = 1.f / (1.f + __expf(-zpre));
        float n = tanhf(xn + r * hn);

        float hprev = 0.f;
        if (t > 0)
            hprev = htpack[(size_t)((t - 1) & 1) * (HH * BB)
                           + (size_t)(j >> 2) * (BB * 4) + b * 4 + (j & 3)];
        float hnew = (1.f - z) * n + z * hprev;

        out[(size_t)b * (TT * HH) + (size_t)t * HH + j] = hnew;
        htpack[(size_t)(t & 1) * (HH * BB)
               + (size_t)(j >> 2) * (BB * 4) + b * 4 + (j & 3)] = hnew;
    }
}

extern "C" void kernel_launch(void* const* d_in, const int* in_sizes, int n_in,
                              void* d_out, int out_size, void* d_ws, size_t ws_size,
                              hipStream_t stream) {
    (void)in_sizes; (void)n_in; (void)ws_size; (void)out_size;

    const float* x    = (const float*)d_in[0];
    const float* Wir  = (const float*)d_in[1];
    const float* bir  = (const float*)d_in[2];
    const float* Whr  = (const float*)d_in[3];
    const float* bhr  = (const float*)d_in[4];
    const float* Wiz  = (const float*)d_in[5];
    const float* biz  = (const float*)d_in[6];
    const float* Whz  = (const float*)d_in[7];
    const float* bhz  = (const float*)d_in[8];
    const float* Win  = (const float*)d_in[9];
    const float* bin_ = (const float*)d_in[10];
    const float* Whn  = (const float*)d_in[11];
    const float* bhn  = (const float*)d_in[12];
    float* out    = (float*)d_out;
    float* htpack = (float*)d_ws;   // 2 * 1024 * 64 * 4B = 512KB double buffer

    for (int t = 0; t < TT; ++t) {
        gru_step<<<dim3(HH / JB), dim3(512), 0, stream>>>(
            x, Wir, Whr, Wiz, Whz, Win, Whn,
            bir, bhr, biz, bhz, bin_, bhn, out, htpack, t);
    }
}